// Round 3
// baseline (672.434 us; speedup 1.0000x reference)
//
#include <hip/hip_runtime.h>

// ---------------------------------------------------------------------------
// N=400000, E=2000000, B=8, C_IN=4, N_EDGE_TYPE=5, N_NODE_TYPE=7, C_OUT=32,
// TEMB_CH=512, AVG_DEGREE=5, fan=55.
//
// Strategy (main path): materialize agg[N][5][16] (line-aligned buckets) with
// 5 fire-and-forget float atomics per edge (avg ~1 edge per bucket -> no
// same-address serialization), then a dense streaming node kernel:
// out[n] = agg[n] @ W / 5 + inj[batch[n]].  No CSR, no output atomics.
// Fallback path (small ws): R1-style direct atomic scatter into out.
// ---------------------------------------------------------------------------

// ---- temb stage 1 partials: emb @ W1 -> h1acc (pre-bias/swish) ------------
__global__ __launch_bounds__(64) void temb1_kernel(
    const float* __restrict__ t, const float* __restrict__ W1,
    float* __restrict__ h1acc)
{
    int jb = blockIdx.x & 7, ks = blockIdx.x >> 3;   // 8 j-tiles x 4 k-slices
    __shared__ float embs[8][32];
    int tid = threadIdx.x;
    const float kStep = 9.210340371976184f / 63.0f;  // ln(10000)/(half-1)
    for (int i = tid; i < 256; i += 64) {
        int b = i >> 5, kk = i & 31;
        int k = ks * 32 + kk;
        float v;
        if (k < 64) v = sinf(t[b] * expf(-(float)k * kStep));
        else        v = cosf(t[b] * expf(-(float)(k - 64) * kStep));
        embs[b][kk] = v;
    }
    __syncthreads();
    int j = jb * 64 + tid;
    float acc[8] = {};
    for (int kk = 0; kk < 32; ++kk) {
        float w = W1[(ks * 32 + kk) * 512 + j];
#pragma unroll
        for (int b = 0; b < 8; ++b) acc[b] += embs[b][kk] * w;
    }
#pragma unroll
    for (int b = 0; b < 8; ++b) atomicAdd(&h1acc[b * 512 + j], acc[b]);
}

// ---- temb stage 2 partials: swish(h1+b1) @ W2 -> h2acc --------------------
__global__ __launch_bounds__(64) void temb2_kernel(
    const float* __restrict__ h1acc, const float* __restrict__ b1,
    const float* __restrict__ W2, float* __restrict__ h2acc)
{
    int jb = blockIdx.x & 7, ks = blockIdx.x >> 3;   // 8 j-tiles x 8 k-slices
    __shared__ float h1s[8][64];
    int tid = threadIdx.x;
    for (int i = tid; i < 512; i += 64) {
        int b = i >> 6, kk = i & 63;
        int k = ks * 64 + kk;
        float v = h1acc[b * 512 + k] + b1[k];
        h1s[b][kk] = v / (1.0f + expf(-v));          // swish
    }
    __syncthreads();
    int j = jb * 64 + tid;
    float acc[8] = {};
    for (int kk = 0; kk < 64; ++kk) {
        float w = W2[(ks * 64 + kk) * 512 + j];
#pragma unroll
        for (int b = 0; b < 8; ++b) acc[b] += h1s[b][kk] * w;
    }
#pragma unroll
    for (int b = 0; b < 8; ++b) atomicAdd(&h2acc[b * 512 + j], acc[b]);
}

// ---- temb stage 3 partials: swish(h2+b2) @ W_temb -> inj[8,32] ------------
__global__ __launch_bounds__(256) void temb3_kernel(
    const float* __restrict__ h2acc, const float* __restrict__ b2,
    const float* __restrict__ Wt, float* __restrict__ inj)
{
    int ks = blockIdx.x;                              // 8 k-slices
    __shared__ float sws[8][64];
    int tid = threadIdx.x;
    for (int i = tid; i < 512; i += 256) {
        int b = i >> 6, kk = i & 63;
        int k = ks * 64 + kk;
        float v = h2acc[b * 512 + k] + b2[k];
        sws[b][kk] = v / (1.0f + expf(-v));           // swish(temb)
    }
    __syncthreads();
    int b = tid >> 5, c = tid & 31;
    float acc = 0.f;
    for (int kk = 0; kk < 64; ++kk)
        acc += sws[b][kk] * Wt[(ks * 64 + kk) * 32 + c];
    atomicAdd(&inj[tid], acc);
}

// ---- edge aggregation: agg[row][T][0:4] += x[col]; agg[row][T][4+nt] += 1 -
// Bucket stride 16 floats = one 64B line; all 5 atomics of an edge hit the
// same line. Fire-and-forget (no return) -> no latency dependency.
__global__ __launch_bounds__(256) void edge_agg_kernel(
    const int* __restrict__ ei, const int* __restrict__ etype,
    const int* __restrict__ ntype, const float* __restrict__ x,
    float* __restrict__ agg, int E)
{
    int e = blockIdx.x * 256 + threadIdx.x;
    if (e >= E) return;
    int row = ei[e], col = ei[E + e];
    int T = etype[e], nt = ntype[col];
    float4 xv = ((const float4*)x)[col];
    float* b = agg + (size_t)row * 80 + T * 16;
    atomicAdd(b + 0, xv.x);
    atomicAdd(b + 1, xv.y);
    atomicAdd(b + 2, xv.z);
    atomicAdd(b + 3, xv.w);
    atomicAdd(b + 4 + nt, 1.0f);
}

// ---- node kernel: out[n] = agg[n] @ W / 5 + inj[batch[n]] -----------------
// 8 threads/node, 4 channels each; agg read as aligned float4; one float4
// store per thread. Streaming, no atomics.
__global__ __launch_bounds__(256) void node_kernel(
    const float* __restrict__ agg, const float* __restrict__ Wc,
    const int* __restrict__ batch, const float* __restrict__ inj,
    float* __restrict__ out, int N)
{
    __shared__ float Ws[55 * 32];
    for (int i = threadIdx.x; i < 55 * 32; i += 256) Ws[i] = Wc[i];
    __syncthreads();
    int gid = blockIdx.x * 256 + threadIdx.x;
    if (gid >= N * 8) return;
    int n = gid >> 3, q = gid & 7;                    // channel quad
    const float4* a4 = (const float4*)(agg + (size_t)n * 80);
    float4 acc = {0.f, 0.f, 0.f, 0.f};
#pragma unroll
    for (int T = 0; T < 5; ++T) {
        float4 r0 = a4[T * 4 + 0];
        float4 r1 = a4[T * 4 + 1];
        float4 r2 = a4[T * 4 + 2];
        float av[11] = {r0.x, r0.y, r0.z, r0.w,
                        r1.x, r1.y, r1.z, r1.w,
                        r2.x, r2.y, r2.z};
        const float4* wT = (const float4*)Ws + (T * 11) * 8 + q;
#pragma unroll
        for (int f = 0; f < 11; ++f) {
            float a = av[f];
            float4 w = wT[f * 8];
            acc.x += a * w.x;
            acc.y += a * w.y;
            acc.z += a * w.z;
            acc.w += a * w.w;
        }
    }
    int b = batch[n];
    float4 iv = ((const float4*)inj)[b * 8 + q];
    float4 o;
    o.x = iv.x + 0.2f * acc.x;
    o.y = iv.y + 0.2f * acc.y;
    o.z = iv.z + 0.2f * acc.z;
    o.w = iv.w + 0.2f * acc.w;
    ((float4*)out)[gid] = o;
}

// ---- fallback (small ws): out init + direct atomic scatter (R1 style) -----
__global__ __launch_bounds__(256) void init_kernel(
    const int* __restrict__ batch_id, const float* __restrict__ inj,
    float4* __restrict__ out, int N)
{
    int gid = blockIdx.x * 256 + threadIdx.x;
    if (gid >= N * 8) return;
    int n = gid >> 3, q = gid & 7;
    int b = batch_id[n];
    out[gid] = ((const float4*)inj)[b * 8 + q];
}

__global__ __launch_bounds__(256) void edge_direct_kernel(
    const int* __restrict__ ei, const int* __restrict__ etype,
    const int* __restrict__ ntype, const float* __restrict__ x,
    const float* __restrict__ Wc, float* __restrict__ out, int E)
{
    __shared__ float Ws[55 * 32];
    for (int i = threadIdx.x; i < 55 * 32; i += 256) Ws[i] = Wc[i];
    __syncthreads();
    unsigned total = (unsigned)E * 32u;
    unsigned stride = gridDim.x * 256u;
    for (unsigned idx = blockIdx.x * 256u + threadIdx.x; idx < total;
         idx += stride) {
        int e = (int)(idx >> 5);
        int c = (int)(idx & 31);
        int row = ei[e];
        int col = ei[E + e];
        int T = etype[e];
        int nt = ntype[col];
        float4 xv = ((const float4*)x)[col];
        const float* wb = Ws + T * 352;
        float y = xv.x * wb[c] + xv.y * wb[32 + c] + xv.z * wb[64 + c] +
                  xv.w * wb[96 + c] + wb[(4 + nt) * 32 + c];
        atomicAdd(out + (size_t)row * 32 + c, y * 0.2f);
    }
}

extern "C" void kernel_launch(void* const* d_in, const int* in_sizes, int n_in,
                              void* d_out, int out_size, void* d_ws, size_t ws_size,
                              hipStream_t stream) {
    const float* x     = (const float*)d_in[0];   // [N,4]
    const float* t     = (const float*)d_in[1];   // [8]
    const int*   ei    = (const int*)d_in[2];     // [2,E]
    const int*   etype = (const int*)d_in[3];     // [E]
    const int*   ntype = (const int*)d_in[4];     // [N]
    const int*   batch = (const int*)d_in[5];     // [N]
    const float* Wc    = (const float*)d_in[6];   // [55,32]
    const float* W1    = (const float*)d_in[7];   // [128,512]
    const float* b1    = (const float*)d_in[8];   // [512]
    const float* W2    = (const float*)d_in[9];   // [512,512]
    const float* b2    = (const float*)d_in[10];  // [512]
    const float* Wt    = (const float*)d_in[11];  // [512,32]
    float* out = (float*)d_out;

    int E = in_sizes[3];
    int N = in_sizes[4];

    size_t aggFloats = (size_t)N * 80;            // agg[N][5][16]
    size_t needBytes = (aggFloats + 8448) * 4;    // + temb buffers

    if (ws_size >= needBytes) {
        float* agg   = (float*)d_ws;
        float* h1acc = agg + aggFloats;           // 4096
        float* h2acc = h1acc + 4096;              // 4096
        float* inj   = h2acc + 4096;              // 256

        hipMemsetAsync(d_ws, 0, needBytes, stream);

        temb1_kernel<<<32, 64, 0, stream>>>(t, W1, h1acc);
        temb2_kernel<<<64, 64, 0, stream>>>(h1acc, b1, W2, h2acc);
        temb3_kernel<<<8, 256, 0, stream>>>(h2acc, b2, Wt, inj);

        edge_agg_kernel<<<(E + 255) / 256, 256, 0, stream>>>(
            ei, etype, ntype, x, agg, E);
        node_kernel<<<(N * 8 + 255) / 256, 256, 0, stream>>>(
            agg, Wc, batch, inj, out, N);
    } else {
        // fallback: direct atomic scatter (R1), temb only in ws
        float* h1acc = (float*)d_ws;              // 4096
        float* h2acc = h1acc + 4096;              // 4096
        float* inj   = h2acc + 4096;              // 256

        hipMemsetAsync(d_ws, 0, 8448 * 4, stream);

        temb1_kernel<<<32, 64, 0, stream>>>(t, W1, h1acc);
        temb2_kernel<<<64, 64, 0, stream>>>(h1acc, b1, W2, h2acc);
        temb3_kernel<<<8, 256, 0, stream>>>(h2acc, b2, Wt, inj);

        init_kernel<<<(N * 8 + 255) / 256, 256, 0, stream>>>(
            batch, inj, (float4*)out, N);
        edge_direct_kernel<<<16384, 256, 0, stream>>>(
            ei, etype, ntype, x, Wc, out, E);
    }
}

// Round 4
// 613.483 us; speedup vs baseline: 1.0961x; 1.0961x over previous
//
#include <hip/hip_runtime.h>

// ---------------------------------------------------------------------------
// N=400000, E=2000000, B=8, C_IN=4, N_EDGE_TYPE=5, N_NODE_TYPE=7, C_OUT=32,
// TEMB_CH=512, AVG_DEGREE=5.
//
// Pipeline: bucket edges by dst-node/256 (hist -> scan -> bin with per-block
// contiguous regions, full-line friendly writes), then one block per bucket
// accumulates into a 256x33 LDS out-tile with LDS float atomics (no global
// float atomics at all), epilogue adds inj[batch] and streams out coalesced.
// HW model from R1-R3: global atomics cap ~300G/s L2-resident, ~20G/s when
// not; partial-line multi-XCD stores bounce 64B lines (R2: 132MB for 8MB).
// ---------------------------------------------------------------------------

#define NBMAX 2048          // max buckets supported (N <= 524288)
#define CHUNK 8192          // edges per bin-kernel block

// ---- temb stage 1 partials: emb @ W1 -> h1acc (pre-bias/swish) ------------
__global__ __launch_bounds__(64) void temb1_kernel(
    const float* __restrict__ t, const float* __restrict__ W1,
    float* __restrict__ h1acc)
{
    int jb = blockIdx.x & 7, ks = blockIdx.x >> 3;   // 8 j-tiles x 4 k-slices
    __shared__ float embs[8][32];
    int tid = threadIdx.x;
    const float kStep = 9.210340371976184f / 63.0f;  // ln(10000)/(half-1)
    for (int i = tid; i < 256; i += 64) {
        int b = i >> 5, kk = i & 31;
        int k = ks * 32 + kk;
        float v;
        if (k < 64) v = sinf(t[b] * expf(-(float)k * kStep));
        else        v = cosf(t[b] * expf(-(float)(k - 64) * kStep));
        embs[b][kk] = v;
    }
    __syncthreads();
    int j = jb * 64 + tid;
    float acc[8] = {};
    for (int kk = 0; kk < 32; ++kk) {
        float w = W1[(ks * 32 + kk) * 512 + j];
#pragma unroll
        for (int b = 0; b < 8; ++b) acc[b] += embs[b][kk] * w;
    }
#pragma unroll
    for (int b = 0; b < 8; ++b) atomicAdd(&h1acc[b * 512 + j], acc[b]);
}

// ---- temb stage 2 partials: swish(h1+b1) @ W2 -> h2acc --------------------
__global__ __launch_bounds__(64) void temb2_kernel(
    const float* __restrict__ h1acc, const float* __restrict__ b1,
    const float* __restrict__ W2, float* __restrict__ h2acc)
{
    int jb = blockIdx.x & 7, ks = blockIdx.x >> 3;   // 8 j-tiles x 8 k-slices
    __shared__ float h1s[8][64];
    int tid = threadIdx.x;
    for (int i = tid; i < 512; i += 64) {
        int b = i >> 6, kk = i & 63;
        int k = ks * 64 + kk;
        float v = h1acc[b * 512 + k] + b1[k];
        h1s[b][kk] = v / (1.0f + expf(-v));          // swish
    }
    __syncthreads();
    int j = jb * 64 + tid;
    float acc[8] = {};
    for (int kk = 0; kk < 64; ++kk) {
        float w = W2[(ks * 64 + kk) * 512 + j];
#pragma unroll
        for (int b = 0; b < 8; ++b) acc[b] += h1s[b][kk] * w;
    }
#pragma unroll
    for (int b = 0; b < 8; ++b) atomicAdd(&h2acc[b * 512 + j], acc[b]);
}

// ---- temb stage 3 partials: swish(h2+b2) @ W_temb -> inj[8,32] ------------
__global__ __launch_bounds__(256) void temb3_kernel(
    const float* __restrict__ h2acc, const float* __restrict__ b2,
    const float* __restrict__ Wt, float* __restrict__ inj)
{
    int ks = blockIdx.x;                              // 8 k-slices
    __shared__ float sws[8][64];
    int tid = threadIdx.x;
    for (int i = tid; i < 512; i += 256) {
        int b = i >> 6, kk = i & 63;
        int k = ks * 64 + kk;
        float v = h2acc[b * 512 + k] + b2[k];
        sws[b][kk] = v / (1.0f + expf(-v));           // swish(temb)
    }
    __syncthreads();
    int b = tid >> 5, c = tid & 31;
    float acc = 0.f;
    for (int kk = 0; kk < 64; ++kk)
        acc += sws[b][kk] * Wt[(ks * 64 + kk) * 32 + c];
    atomicAdd(&inj[tid], acc);
}

// ---- bucket histogram (LDS-aggregated) ------------------------------------
__global__ __launch_bounds__(256) void hist_kernel(
    const int* __restrict__ ei, int* __restrict__ hist, int E, int NB)
{
    __shared__ int h[NBMAX];
    int tid = threadIdx.x;
    for (int i = tid; i < NB; i += 256) h[i] = 0;
    __syncthreads();
    for (int e = blockIdx.x * 256 + tid; e < E; e += gridDim.x * 256)
        atomicAdd(&h[ei[e] >> 8], 1);
    __syncthreads();
    for (int i = tid; i < NB; i += 256) {
        int v = h[i];
        if (v) atomicAdd(&hist[i], v);
    }
}

// ---- exclusive scan of hist -> bstart, gcur (single block) ----------------
__global__ __launch_bounds__(1024) void scan_kernel(
    const int* __restrict__ hist, int* __restrict__ bstart,
    int* __restrict__ gcur, int NB, int E)
{
    __shared__ int s[1024];
    int tid = threadIdx.x;
    int i0 = 2 * tid, i1 = 2 * tid + 1;
    int v0 = (i0 < NB) ? hist[i0] : 0;
    int v1 = (i1 < NB) ? hist[i1] : 0;
    int p = v0 + v1;
    s[tid] = p; __syncthreads();
    for (int off = 1; off < 1024; off <<= 1) {
        int u = (tid >= off) ? s[tid - off] : 0;
        __syncthreads();
        s[tid] += u;
        __syncthreads();
    }
    int base = s[tid] - p;                            // exclusive pair base
    if (i0 < NB) { bstart[i0] = base;      gcur[i0] = base; }
    if (i1 < NB) { bstart[i1] = base + v0; gcur[i1] = base + v0; }
    if (tid == 0) bstart[NB] = E;
}

// ---- bin: per-block chunk -> per-bucket contiguous record regions ---------
// rec = { col | T<<19 | nt<<22 , lrow }. Each block owns disjoint regions
// (single-writer lines -> no cross-XCD partial-line bouncing).
__global__ __launch_bounds__(256) void bin_kernel(
    const int* __restrict__ ei, const int* __restrict__ etype,
    const int* __restrict__ ntype, int* __restrict__ gcur,
    uint2* __restrict__ rec, int E, int NB)
{
    __shared__ int histL[NBMAX];
    __shared__ int gbaseL[NBMAX];
    __shared__ int lcur[NBMAX];
    int tid = threadIdx.x;
    int base = blockIdx.x * CHUNK;
    for (int i = tid; i < NB; i += 256) histL[i] = 0;
    __syncthreads();
    for (int i = tid; i < CHUNK; i += 256) {
        int e = base + i;
        if (e < E) atomicAdd(&histL[ei[e] >> 8], 1);
    }
    __syncthreads();
    for (int i = tid; i < NB; i += 256) {
        int h = histL[i];
        gbaseL[i] = h ? atomicAdd(&gcur[i], h) : 0;
        lcur[i] = 0;
    }
    __syncthreads();
    for (int i = tid; i < CHUNK; i += 256) {
        int e = base + i;
        if (e >= E) continue;
        int row = ei[e], col = ei[E + e];
        int T = etype[e], nt = ntype[col];
        int b = row >> 8;
        int pos = atomicAdd(&lcur[b], 1);
        uint2 r;
        r.x = (unsigned)col | ((unsigned)T << 19) | ((unsigned)nt << 22);
        r.y = (unsigned)(row & 255);
        rec[gbaseL[b] + pos] = r;
    }
}

// ---- final: one block per bucket; LDS out-tile + LDS float atomics --------
__global__ __launch_bounds__(256) void final_kernel(
    const int* __restrict__ bstart, const uint2* __restrict__ rec,
    const float* __restrict__ x, const float* __restrict__ Wc,
    const int* __restrict__ batch, const float* __restrict__ inj,
    float* __restrict__ out, int N)
{
    __shared__ float tile[256 * 33];      // pad 33: spreads atomic banks
    __shared__ float Ws[55 * 36];         // rows padded to 9 float4s
    int tid = threadIdx.x;
    for (int i = tid; i < 55 * 32; i += 256) {
        int j = i >> 5, c = i & 31;
        Ws[j * 36 + c] = Wc[i];
    }
    for (int i = tid; i < 256 * 33; i += 256) tile[i] = 0.f;
    __syncthreads();

    int b = blockIdx.x;
    int s = bstart[b], e = bstart[b + 1];
    int rot = tid & 7;
    for (int i = s + tid; i < e; i += 256) {
        uint2 r = rec[i];
        int col  = r.x & 0x7FFFF;
        int T    = (r.x >> 19) & 7;
        int nt   = (r.x >> 22) & 7;
        int lrow = (int)r.y;
        float4 xv = ((const float4*)x)[col];
        const float* wT = Ws + T * 396;               // T * 11 * 36
        float* trow = tile + lrow * 33;
#pragma unroll
        for (int k = 0; k < 8; ++k) {
            int c4 = (k + rot) & 7;
            float4 w0 = *(const float4*)(wT + 0 * 36 + c4 * 4);
            float4 w1 = *(const float4*)(wT + 1 * 36 + c4 * 4);
            float4 w2 = *(const float4*)(wT + 2 * 36 + c4 * 4);
            float4 w3 = *(const float4*)(wT + 3 * 36 + c4 * 4);
            float4 w4 = *(const float4*)(wT + (4 + nt) * 36 + c4 * 4);
            float vx = xv.x * w0.x + xv.y * w1.x + xv.z * w2.x + xv.w * w3.x + w4.x;
            float vy = xv.x * w0.y + xv.y * w1.y + xv.z * w2.y + xv.w * w3.y + w4.y;
            float vz = xv.x * w0.z + xv.y * w1.z + xv.z * w2.z + xv.w * w3.z + w4.z;
            float vw = xv.x * w0.w + xv.y * w1.w + xv.z * w2.w + xv.w * w3.w + w4.w;
            atomicAdd(&trow[c4 * 4 + 0], vx);
            atomicAdd(&trow[c4 * 4 + 1], vy);
            atomicAdd(&trow[c4 * 4 + 2], vz);
            atomicAdd(&trow[c4 * 4 + 3], vw);
        }
    }
    __syncthreads();

    int nodes = N - b * 256; if (nodes > 256) nodes = 256;
    for (int i = tid; i < nodes * 8; i += 256) {
        int nl = i >> 3, q = i & 7;
        int n = b * 256 + nl;
        int bb = batch[n];
        float4 iv = ((const float4*)inj)[bb * 8 + q];
        const float* tr = tile + nl * 33 + q * 4;
        float4 o;
        o.x = iv.x + 0.2f * tr[0];
        o.y = iv.y + 0.2f * tr[1];
        o.z = iv.z + 0.2f * tr[2];
        o.w = iv.w + 0.2f * tr[3];
        ((float4*)out)[(size_t)n * 8 + q] = o;
    }
}

// ---- fallback (small ws / huge N): out init + direct atomic scatter -------
__global__ __launch_bounds__(256) void init_kernel(
    const int* __restrict__ batch_id, const float* __restrict__ inj,
    float4* __restrict__ out, int N)
{
    int gid = blockIdx.x * 256 + threadIdx.x;
    if (gid >= N * 8) return;
    int n = gid >> 3, q = gid & 7;
    int b = batch_id[n];
    out[gid] = ((const float4*)inj)[b * 8 + q];
}

__global__ __launch_bounds__(256) void edge_direct_kernel(
    const int* __restrict__ ei, const int* __restrict__ etype,
    const int* __restrict__ ntype, const float* __restrict__ x,
    const float* __restrict__ Wc, float* __restrict__ out, int E)
{
    __shared__ float Ws[55 * 32];
    for (int i = threadIdx.x; i < 55 * 32; i += 256) Ws[i] = Wc[i];
    __syncthreads();
    unsigned total = (unsigned)E * 32u;
    unsigned stride = gridDim.x * 256u;
    for (unsigned idx = blockIdx.x * 256u + threadIdx.x; idx < total;
         idx += stride) {
        int e = (int)(idx >> 5);
        int c = (int)(idx & 31);
        int row = ei[e];
        int col = ei[E + e];
        int T = etype[e];
        int nt = ntype[col];
        float4 xv = ((const float4*)x)[col];
        const float* wb = Ws + T * 352;
        float y = xv.x * wb[c] + xv.y * wb[32 + c] + xv.z * wb[64 + c] +
                  xv.w * wb[96 + c] + wb[(4 + nt) * 32 + c];
        atomicAdd(out + (size_t)row * 32 + c, y * 0.2f);
    }
}

extern "C" void kernel_launch(void* const* d_in, const int* in_sizes, int n_in,
                              void* d_out, int out_size, void* d_ws, size_t ws_size,
                              hipStream_t stream) {
    const float* x     = (const float*)d_in[0];   // [N,4]
    const float* t     = (const float*)d_in[1];   // [8]
    const int*   ei    = (const int*)d_in[2];     // [2,E]
    const int*   etype = (const int*)d_in[3];     // [E]
    const int*   ntype = (const int*)d_in[4];     // [N]
    const int*   batch = (const int*)d_in[5];     // [N]
    const float* Wc    = (const float*)d_in[6];   // [55,32]
    const float* W1    = (const float*)d_in[7];   // [128,512]
    const float* b1    = (const float*)d_in[8];   // [512]
    const float* W2    = (const float*)d_in[9];   // [512,512]
    const float* b2    = (const float*)d_in[10];  // [512]
    const float* Wt    = (const float*)d_in[11];  // [512,32]
    float* out = (float*)d_out;

    int E = in_sizes[3];
    int N = in_sizes[4];
    int NB = (N + 255) / 256;                     // node buckets

    // ws layout (float units): temb 8448 | hist NB | bstart NB+1 | gcur NB | rec
    float* ws    = (float*)d_ws;
    float* h1acc = ws;                            // 4096
    float* h2acc = ws + 4096;                     // 4096
    float* inj   = ws + 8192;                     // 256
    int*   hist  = (int*)(ws + 8448);             // NB (zeroed by memset)
    int*   bstart= hist + NB;                     // NB+1
    int*   gcur  = bstart + NB + 1;               // NB
    size_t recOff = (size_t)(8448 + 3 * NB + 1);
    recOff = (recOff + 1) & ~(size_t)1;           // 8B align
    uint2* rec   = (uint2*)(ws + recOff);         // E records

    size_t needBytes = recOff * 4 + (size_t)E * 8;

    if (NB <= NBMAX && ws_size >= needBytes) {
        hipMemsetAsync(d_ws, 0, (size_t)(8448 + NB) * 4, stream);

        temb1_kernel<<<32, 64, 0, stream>>>(t, W1, h1acc);
        temb2_kernel<<<64, 64, 0, stream>>>(h1acc, b1, W2, h2acc);
        temb3_kernel<<<8, 256, 0, stream>>>(h2acc, b2, Wt, inj);

        hist_kernel<<<256, 256, 0, stream>>>(ei, hist, E, NB);
        scan_kernel<<<1, 1024, 0, stream>>>(hist, bstart, gcur, NB, E);
        int nchunks = (E + CHUNK - 1) / CHUNK;
        bin_kernel<<<nchunks, 256, 0, stream>>>(ei, etype, ntype, gcur, rec, E, NB);
        final_kernel<<<NB, 256, 0, stream>>>(bstart, rec, x, Wc, batch, inj, out, N);
    } else {
        float* inj2 = ws + 8192;
        hipMemsetAsync(d_ws, 0, 8448 * 4, stream);
        temb1_kernel<<<32, 64, 0, stream>>>(t, W1, h1acc);
        temb2_kernel<<<64, 64, 0, stream>>>(h1acc, b1, W2, h2acc);
        temb3_kernel<<<8, 256, 0, stream>>>(h2acc, b2, Wt, inj2);
        init_kernel<<<(N * 8 + 255) / 256, 256, 0, stream>>>(
            batch, inj2, (float4*)out, N);
        edge_direct_kernel<<<16384, 256, 0, stream>>>(
            ei, etype, ntype, x, Wc, out, E);
    }
}

// Round 5
// 589.952 us; speedup vs baseline: 1.1398x; 1.0399x over previous
//
#include <hip/hip_runtime.h>

// ---------------------------------------------------------------------------
// N=400000, E=2000000, B=8, C_IN=4, N_EDGE_TYPE=5, N_NODE_TYPE=7, C_OUT=32.
//
// HW model (measured R1-R4): global atomic dword-RMW caps ~300G/s (L2-warm)
// and ~20G/s when 64B lines thrash HBM; sub-256B scattered global writes
// bounce lines across XCDs (R2/R4); per-edge cost must be ~5 ops not 32.
//
// Pipeline: two-level write-combined binning (edges -> 8192-node ranges ->
// 256-node buckets) using LDS staging + batched contiguous flushes (no
// per-record global writes), then one block per bucket accumulates agg
// (4 feature sums + 7 type counts per (node,T)) with 5 LDS atomics/edge and
// finishes with a dense 55x32 matvec epilogue + inj[batch], single coalesced
// out write. Zero global float atomics.
// ---------------------------------------------------------------------------

#define NRMAX   56        // max ranges (N <= 458752)
#define R1CAP   65536     // records per range region
#define R2CAP   2048      // records per bucket region

// ---- temb stage 1 partials: emb @ W1 -> h1acc (pre-bias/swish) ------------
__global__ __launch_bounds__(64) void temb1_kernel(
    const float* __restrict__ t, const float* __restrict__ W1,
    float* __restrict__ h1acc)
{
    int jb = blockIdx.x & 7, ks = blockIdx.x >> 3;
    __shared__ float embs[8][32];
    int tid = threadIdx.x;
    const float kStep = 9.210340371976184f / 63.0f;
    for (int i = tid; i < 256; i += 64) {
        int b = i >> 5, kk = i & 31;
        int k = ks * 32 + kk;
        float v;
        if (k < 64) v = sinf(t[b] * expf(-(float)k * kStep));
        else        v = cosf(t[b] * expf(-(float)(k - 64) * kStep));
        embs[b][kk] = v;
    }
    __syncthreads();
    int j = jb * 64 + tid;
    float acc[8] = {};
    for (int kk = 0; kk < 32; ++kk) {
        float w = W1[(ks * 32 + kk) * 512 + j];
#pragma unroll
        for (int b = 0; b < 8; ++b) acc[b] += embs[b][kk] * w;
    }
#pragma unroll
    for (int b = 0; b < 8; ++b) atomicAdd(&h1acc[b * 512 + j], acc[b]);
}

// ---- temb stage 2 partials: swish(h1+b1) @ W2 -> h2acc --------------------
__global__ __launch_bounds__(64) void temb2_kernel(
    const float* __restrict__ h1acc, const float* __restrict__ b1,
    const float* __restrict__ W2, float* __restrict__ h2acc)
{
    int jb = blockIdx.x & 7, ks = blockIdx.x >> 3;
    __shared__ float h1s[8][64];
    int tid = threadIdx.x;
    for (int i = tid; i < 512; i += 64) {
        int b = i >> 6, kk = i & 63;
        int k = ks * 64 + kk;
        float v = h1acc[b * 512 + k] + b1[k];
        h1s[b][kk] = v / (1.0f + expf(-v));
    }
    __syncthreads();
    int j = jb * 64 + tid;
    float acc[8] = {};
    for (int kk = 0; kk < 64; ++kk) {
        float w = W2[(ks * 64 + kk) * 512 + j];
#pragma unroll
        for (int b = 0; b < 8; ++b) acc[b] += h1s[b][kk] * w;
    }
#pragma unroll
    for (int b = 0; b < 8; ++b) atomicAdd(&h2acc[b * 512 + j], acc[b]);
}

// ---- temb stage 3 partials: swish(h2+b2) @ W_temb -> inj[8,32] ------------
__global__ __launch_bounds__(256) void temb3_kernel(
    const float* __restrict__ h2acc, const float* __restrict__ b2,
    const float* __restrict__ Wt, float* __restrict__ inj)
{
    int ks = blockIdx.x;
    __shared__ float sws[8][64];
    int tid = threadIdx.x;
    for (int i = tid; i < 512; i += 256) {
        int b = i >> 6, kk = i & 63;
        int k = ks * 64 + kk;
        float v = h2acc[b * 512 + k] + b2[k];
        sws[b][kk] = v / (1.0f + expf(-v));
    }
    __syncthreads();
    int b = tid >> 5, c = tid & 31;
    float acc = 0.f;
    for (int kk = 0; kk < 64; ++kk)
        acc += sws[b][kk] * Wt[(ks * 64 + kk) * 32 + c];
    atomicAdd(&inj[tid], acc);
}

// ---- bin level 1: edges -> 8192-node ranges, write-combined ---------------
// rec = { col | T<<19 | nt<<22 , row & 8191 }. Per round (2048 edges) stage
// in per-range LDS buffers, flush each range's batch as one contiguous chunk
// (wave-wide stores) with a single bump atomic.
__global__ __launch_bounds__(1024) void bin1_kernel(
    const int* __restrict__ ei, const int* __restrict__ etype,
    const int* __restrict__ ntype, int* __restrict__ gcnt1,
    uint2* __restrict__ rec1, int E, int NR, int slab)
{
    __shared__ uint2 buf[NRMAX * 128];
    __shared__ int cnt[NRMAX];
    int tid = threadIdx.x;
    int s0 = blockIdx.x * slab;
    int send = min(s0 + slab, E);
    for (int base = s0; base < send; base += 2048) {
        for (int i = tid; i < NR; i += 1024) cnt[i] = 0;
        __syncthreads();
#pragma unroll
        for (int k = 0; k < 2; ++k) {
            int e = base + k * 1024 + tid;
            if (e < send) {
                int row = ei[e], col = ei[E + e];
                int T = etype[e], nt = ntype[col];
                int r = row >> 13;
                int pos = atomicAdd(&cnt[r], 1);
                if (pos < 128) {
                    uint2 rc;
                    rc.x = (unsigned)col | ((unsigned)T << 19) | ((unsigned)nt << 22);
                    rc.y = (unsigned)(row & 8191);
                    buf[r * 128 + pos] = rc;
                }
            }
        }
        __syncthreads();
        int wid = tid >> 6, lane = tid & 63;          // 16 waves
        for (int r = wid; r < NR; r += 16) {
            int pend = min(cnt[r], 128);
            if (pend > 0) {
                int gb = 0;
                if (lane == 0) gb = atomicAdd(&gcnt1[r], pend);
                gb = __shfl(gb, 0);
                if (gb + pend <= R1CAP) {
                    uint2* dst = rec1 + (size_t)r * R1CAP + gb;
                    for (int off = lane; off < pend; off += 64)
                        dst[off] = buf[r * 128 + off];
                }
            }
        }
        __syncthreads();
    }
}

// ---- bin level 2: range records -> 256-node buckets (32 sub/range) --------
__global__ __launch_bounds__(1024) void bin2_kernel(
    const int* __restrict__ gcnt1, const uint2* __restrict__ rec1,
    int* __restrict__ gcnt2, uint2* __restrict__ rec2)
{
    __shared__ uint2 buf[32 * 128];
    __shared__ int cnt[32];
    int tid = threadIdx.x;
    int r = blockIdx.x >> 3, blk = blockIdx.x & 7;    // 8 blocks per range
    int total = min(gcnt1[r], R1CAP);
    int s0 = blk * (R1CAP / 8);
    int send = min(s0 + R1CAP / 8, total);
    const uint2* src = rec1 + (size_t)r * R1CAP;
    for (int base = s0; base < send; base += 2048) {
        if (tid < 32) cnt[tid] = 0;
        __syncthreads();
#pragma unroll
        for (int k = 0; k < 2; ++k) {
            int i = base + k * 1024 + tid;
            if (i < send) {
                uint2 rc = src[i];
                int sb = (rc.y >> 8) & 31;
                int pos = atomicAdd(&cnt[sb], 1);
                if (pos < 128) buf[sb * 128 + pos] = rc;
            }
        }
        __syncthreads();
        int wid = tid >> 6, lane = tid & 63;          // 16 waves, 32 subs
        for (int sb = wid; sb < 32; sb += 16) {
            int pend = min(cnt[sb], 128);
            if (pend > 0) {
                int bucket = r * 32 + sb;
                int gb = 0;
                if (lane == 0) gb = atomicAdd(&gcnt2[bucket], pend);
                gb = __shfl(gb, 0);
                if (gb + pend <= R2CAP) {
                    uint2* dst = rec2 + (size_t)bucket * R2CAP + gb;
                    for (int off = lane; off < pend; off += 64)
                        dst[off] = buf[sb * 128 + off];
                }
            }
        }
        __syncthreads();
    }
}

// ---- consume: block per 256-node bucket; agg in LDS (5 atomics/edge),
// dense 55x32 epilogue, single coalesced out write fused with inj[batch]. ---
__global__ __launch_bounds__(256) void consume_kernel(
    const int* __restrict__ gcnt2, const uint2* __restrict__ rec2,
    const float* __restrict__ x, const float* __restrict__ Wc,
    const int* __restrict__ batch, const float* __restrict__ inj,
    float* __restrict__ out, int N)
{
    __shared__ float tile[256 * 57];   // row stride 57 (odd -> uniform banks)
    int tid = threadIdx.x;
    int b = blockIdx.x;
    for (int i = tid; i < 256 * 57; i += 256) tile[i] = 0.f;
    __syncthreads();

    int cnt = min(gcnt2[b], R2CAP);
    const uint2* src = rec2 + (size_t)b * R2CAP;
#pragma unroll 2
    for (int i = tid; i < cnt; i += 256) {
        uint2 rc = src[i];
        int col = rc.x & 0x7FFFF;
        int T   = (rc.x >> 19) & 7;
        int nt  = (rc.x >> 22) & 7;
        int lrow = (int)(rc.y & 255);
        if (col >= N || T > 4) continue;              // pathological-overflow guard
        float4 xv = ((const float4*)x)[col];
        float* tr = tile + lrow * 57 + T * 11;
        atomicAdd(tr + 0, xv.x);
        atomicAdd(tr + 1, xv.y);
        atomicAdd(tr + 2, xv.z);
        atomicAdd(tr + 3, xv.w);
        atomicAdd(tr + 4 + nt, 1.0f);
    }
    __syncthreads();

    int nodes = N - b * 256; if (nodes > 256) nodes = 256;
    for (int oi = tid; oi < nodes * 8; oi += 256) {
        int nl = oi >> 3, cq = oi & 7;
        int n = b * 256 + nl;
        const float* ar = tile + nl * 57;
        float4 acc = {0.f, 0.f, 0.f, 0.f};
#pragma unroll 5
        for (int f = 0; f < 55; ++f) {
            float a = ar[f];
            float4 w = ((const float4*)(Wc + f * 32))[cq];
            acc.x += a * w.x;
            acc.y += a * w.y;
            acc.z += a * w.z;
            acc.w += a * w.w;
        }
        int bb = batch[n];
        float4 iv = ((const float4*)inj)[bb * 8 + cq];
        float4 o;
        o.x = iv.x + 0.2f * acc.x;
        o.y = iv.y + 0.2f * acc.y;
        o.z = iv.z + 0.2f * acc.z;
        o.w = iv.w + 0.2f * acc.w;
        ((float4*)out)[(size_t)n * 8 + cq] = o;
    }
}

// ---- fallback (guards fail): out init + direct atomic scatter (R1) --------
__global__ __launch_bounds__(256) void init_kernel(
    const int* __restrict__ batch_id, const float* __restrict__ inj,
    float4* __restrict__ out, int N)
{
    int gid = blockIdx.x * 256 + threadIdx.x;
    if (gid >= N * 8) return;
    int n = gid >> 3, q = gid & 7;
    int b = batch_id[n];
    out[gid] = ((const float4*)inj)[b * 8 + q];
}

__global__ __launch_bounds__(256) void edge_direct_kernel(
    const int* __restrict__ ei, const int* __restrict__ etype,
    const int* __restrict__ ntype, const float* __restrict__ x,
    const float* __restrict__ Wc, float* __restrict__ out, int E)
{
    __shared__ float Ws[55 * 32];
    for (int i = threadIdx.x; i < 55 * 32; i += 256) Ws[i] = Wc[i];
    __syncthreads();
    unsigned total = (unsigned)E * 32u;
    unsigned stride = gridDim.x * 256u;
    for (unsigned idx = blockIdx.x * 256u + threadIdx.x; idx < total;
         idx += stride) {
        int e = (int)(idx >> 5);
        int c = (int)(idx & 31);
        int row = ei[e];
        int col = ei[E + e];
        int T = etype[e];
        int nt = ntype[col];
        float4 xv = ((const float4*)x)[col];
        const float* wb = Ws + T * 352;
        float y = xv.x * wb[c] + xv.y * wb[32 + c] + xv.z * wb[64 + c] +
                  xv.w * wb[96 + c] + wb[(4 + nt) * 32 + c];
        atomicAdd(out + (size_t)row * 32 + c, y * 0.2f);
    }
}

extern "C" void kernel_launch(void* const* d_in, const int* in_sizes, int n_in,
                              void* d_out, int out_size, void* d_ws, size_t ws_size,
                              hipStream_t stream) {
    const float* x     = (const float*)d_in[0];   // [N,4]
    const float* t     = (const float*)d_in[1];   // [8]
    const int*   ei    = (const int*)d_in[2];     // [2,E]
    const int*   etype = (const int*)d_in[3];     // [E]
    const int*   ntype = (const int*)d_in[4];     // [N]
    const int*   batch = (const int*)d_in[5];     // [N]
    const float* Wc    = (const float*)d_in[6];   // [55,32]
    const float* W1    = (const float*)d_in[7];   // [128,512]
    const float* b1    = (const float*)d_in[8];   // [512]
    const float* W2    = (const float*)d_in[9];   // [512,512]
    const float* b2    = (const float*)d_in[10];  // [512]
    const float* Wt    = (const float*)d_in[11];  // [512,32]
    float* out = (float*)d_out;

    int E = in_sizes[3];
    int N = in_sizes[4];
    int NR = (N + 8191) >> 13;                    // 8192-node ranges
    int NB = (N + 255) >> 8;                      // 256-node buckets

    // ws layout (4-byte units)
    float* ws    = (float*)d_ws;
    float* h1acc = ws;                            // 4096
    float* h2acc = ws + 4096;                     // 4096
    float* inj   = ws + 8192;                     // 256
    int*   gcnt1 = (int*)(ws + 8448);             // NRMAX slots
    int*   gcnt2 = gcnt1 + NRMAX;                 // NB
    size_t recOff = (size_t)(8448 + NRMAX + NB + 1) & ~(size_t)1;
    uint2* rec1  = (uint2*)(ws + recOff);         // NR * R1CAP
    uint2* rec2  = rec1 + (size_t)NR * R1CAP;     // NB * R2CAP
    size_t needBytes = recOff * 4 +
                       ((size_t)NR * R1CAP + (size_t)NB * R2CAP) * 8;

    bool okay = (NR <= NRMAX) && (E <= NR * (R1CAP * 3 / 4)) &&
                (ws_size >= needBytes);

    if (okay) {
        hipMemsetAsync(d_ws, 0, (size_t)(8448 + NRMAX + NB) * 4, stream);

        temb1_kernel<<<32, 64, 0, stream>>>(t, W1, h1acc);
        temb2_kernel<<<64, 64, 0, stream>>>(h1acc, b1, W2, h2acc);
        temb3_kernel<<<8, 256, 0, stream>>>(h2acc, b2, Wt, inj);

        int slab = (E + 255) / 256;
        bin1_kernel<<<256, 1024, 0, stream>>>(ei, etype, ntype, gcnt1, rec1,
                                              E, NR, slab);
        bin2_kernel<<<NR * 8, 1024, 0, stream>>>(gcnt1, rec1, gcnt2, rec2);
        consume_kernel<<<NB, 256, 0, stream>>>(gcnt2, rec2, x, Wc, batch, inj,
                                               out, N);
    } else {
        hipMemsetAsync(d_ws, 0, 8448 * 4, stream);
        temb1_kernel<<<32, 64, 0, stream>>>(t, W1, h1acc);
        temb2_kernel<<<64, 64, 0, stream>>>(h1acc, b1, W2, h2acc);
        temb3_kernel<<<8, 256, 0, stream>>>(h2acc, b2, Wt, inj);
        init_kernel<<<(N * 8 + 255) / 256, 256, 0, stream>>>(
            batch, inj, (float4*)out, N);
        edge_direct_kernel<<<16384, 256, 0, stream>>>(
            ei, etype, ntype, x, Wc, out, E);
    }
}

// Round 6
// 318.567 us; speedup vs baseline: 2.1108x; 1.8519x over previous
//
#include <hip/hip_runtime.h>

// ---------------------------------------------------------------------------
// N=400000, E=2000000, B=8, C_IN=4, N_EDGE_TYPE=5, N_NODE_TYPE=7, C_OUT=32.
//
// HW model (measured R1-R5):
//  - global atomic dword RMW: ~300G/s when spread (R1), ~20G/s when 64B lines
//    thrash HBM (R3); returning atomics on few hot lines serialize at ~25ns
//    each through the coherence point (R5 bin1 = 313us on 49 counters).
//  - sub-256B multi-writer global stores bounce lines across XCDs (R2/R4).
//  => This pipeline has ZERO global atomics: counting sort with exact
//     precomputed offsets (hist -> 3-kernel scan -> scatter), then per-bucket
//     LDS aggregation (5 LDS atomics/edge) + dense epilogue, single coalesced
//     output write fused with inj[batch_id].
// ---------------------------------------------------------------------------

#define CH     8192        // edges per chunk
#define NBMAX  2048        // max 256-node buckets (N <= 524288)

// ---- temb stage 1 partials: emb @ W1 -> h1acc (pre-bias/swish) ------------
__global__ __launch_bounds__(64) void temb1_kernel(
    const float* __restrict__ t, const float* __restrict__ W1,
    float* __restrict__ h1acc)
{
    int jb = blockIdx.x & 7, ks = blockIdx.x >> 3;
    __shared__ float embs[8][32];
    int tid = threadIdx.x;
    const float kStep = 9.210340371976184f / 63.0f;
    for (int i = tid; i < 256; i += 64) {
        int b = i >> 5, kk = i & 31;
        int k = ks * 32 + kk;
        float v;
        if (k < 64) v = sinf(t[b] * expf(-(float)k * kStep));
        else        v = cosf(t[b] * expf(-(float)(k - 64) * kStep));
        embs[b][kk] = v;
    }
    __syncthreads();
    int j = jb * 64 + tid;
    float acc[8] = {};
    for (int kk = 0; kk < 32; ++kk) {
        float w = W1[(ks * 32 + kk) * 512 + j];
#pragma unroll
        for (int b = 0; b < 8; ++b) acc[b] += embs[b][kk] * w;
    }
#pragma unroll
    for (int b = 0; b < 8; ++b) atomicAdd(&h1acc[b * 512 + j], acc[b]);
}

// ---- temb stage 2 partials: swish(h1+b1) @ W2 -> h2acc --------------------
__global__ __launch_bounds__(64) void temb2_kernel(
    const float* __restrict__ h1acc, const float* __restrict__ b1,
    const float* __restrict__ W2, float* __restrict__ h2acc)
{
    int jb = blockIdx.x & 7, ks = blockIdx.x >> 3;
    __shared__ float h1s[8][64];
    int tid = threadIdx.x;
    for (int i = tid; i < 512; i += 64) {
        int b = i >> 6, kk = i & 63;
        int k = ks * 64 + kk;
        float v = h1acc[b * 512 + k] + b1[k];
        h1s[b][kk] = v / (1.0f + expf(-v));
    }
    __syncthreads();
    int j = jb * 64 + tid;
    float acc[8] = {};
    for (int kk = 0; kk < 64; ++kk) {
        float w = W2[(ks * 64 + kk) * 512 + j];
#pragma unroll
        for (int b = 0; b < 8; ++b) acc[b] += h1s[b][kk] * w;
    }
#pragma unroll
    for (int b = 0; b < 8; ++b) atomicAdd(&h2acc[b * 512 + j], acc[b]);
}

// ---- temb stage 3 partials: swish(h2+b2) @ W_temb -> inj[8,32] ------------
__global__ __launch_bounds__(256) void temb3_kernel(
    const float* __restrict__ h2acc, const float* __restrict__ b2,
    const float* __restrict__ Wt, float* __restrict__ inj)
{
    int ks = blockIdx.x;
    __shared__ float sws[8][64];
    int tid = threadIdx.x;
    for (int i = tid; i < 512; i += 256) {
        int b = i >> 6, kk = i & 63;
        int k = ks * 64 + kk;
        float v = h2acc[b * 512 + k] + b2[k];
        sws[b][kk] = v / (1.0f + expf(-v));
    }
    __syncthreads();
    int b = tid >> 5, c = tid & 31;
    float acc = 0.f;
    for (int kk = 0; kk < 64; ++kk)
        acc += sws[b][kk] * Wt[(ks * 64 + kk) * 32 + c];
    atomicAdd(&inj[tid], acc);
}

// ---- hist: block per chunk; LDS histogram; contiguous row store -----------
__global__ __launch_bounds__(256) void hist_kernel(
    const int* __restrict__ ei, int* __restrict__ counts, int E, int NB)
{
    __shared__ int h[NBMAX];
    int tid = threadIdx.x;
    int c = blockIdx.x;
    for (int i = tid; i < NB; i += 256) h[i] = 0;
    __syncthreads();
    int s = c * CH, e = min(s + CH, E);
    for (int i = s + tid; i < e; i += 256)
        atomicAdd(&h[ei[i] >> 8], 1);
    __syncthreads();
    int* row = counts + (size_t)c * NB;
    for (int i = tid; i < NB; i += 256) row[i] = h[i];
}

// ---- scanA: per-block sums over bucket-major order j = b*NCH + c ----------
__global__ __launch_bounds__(256) void scanA_kernel(
    const int* __restrict__ counts, int* __restrict__ bsums,
    int M, int NB, int NCH)
{
    __shared__ int s[256];
    int tid = threadIdx.x;
    int j0 = blockIdx.x * 2048 + tid * 8;
    int p = 0;
#pragma unroll
    for (int k = 0; k < 8; ++k) {
        int j = j0 + k;
        if (j < M) {
            int b = j / NCH, c = j - b * NCH;
            p += counts[(size_t)c * NB + b];
        }
    }
    s[tid] = p; __syncthreads();
    for (int off = 128; off > 0; off >>= 1) {
        if (tid < off) s[tid] += s[tid + off];
        __syncthreads();
    }
    if (tid == 0) bsums[blockIdx.x] = s[0];
}

// ---- scanB: exclusive scan of block sums (single block, <=1024) -----------
__global__ __launch_bounds__(1024) void scanB_kernel(
    int* __restrict__ bsums, int* __restrict__ bstart, int nblk, int NB, int E)
{
    __shared__ int s[1024];
    int tid = threadIdx.x;
    int v = (tid < nblk) ? bsums[tid] : 0;
    s[tid] = v; __syncthreads();
    for (int off = 1; off < 1024; off <<= 1) {
        int u = (tid >= off) ? s[tid - off] : 0;
        __syncthreads();
        s[tid] += u;
        __syncthreads();
    }
    if (tid < nblk) bsums[tid] = s[tid] - v;          // exclusive
    if (tid == 0) bstart[NB] = E;
}

// ---- scanC: exact base for every (bucket, chunk) region + bstart ----------
__global__ __launch_bounds__(256) void scanC_kernel(
    const int* __restrict__ counts, const int* __restrict__ bsums,
    int* __restrict__ base, int* __restrict__ bstart,
    int M, int NB, int NCH)
{
    __shared__ int s[256];
    int tid = threadIdx.x;
    int j0 = blockIdx.x * 2048 + tid * 8;
    int v[8]; int p = 0;
#pragma unroll
    for (int k = 0; k < 8; ++k) {
        int j = j0 + k;
        v[k] = 0;
        if (j < M) {
            int b = j / NCH, c = j - b * NCH;
            v[k] = counts[(size_t)c * NB + b];
        }
        p += v[k];
    }
    s[tid] = p; __syncthreads();
    for (int off = 1; off < 256; off <<= 1) {
        int u = (tid >= off) ? s[tid - off] : 0;
        __syncthreads();
        s[tid] += u;
        __syncthreads();
    }
    int run = bsums[blockIdx.x] + (s[tid] - p);
#pragma unroll
    for (int k = 0; k < 8; ++k) {
        int j = j0 + k;
        if (j < M) {
            base[j] = run;
            int b = j / NCH, c = j - b * NCH;
            if (c == 0) bstart[b] = run;
            run += v[k];
        }
    }
}

// ---- scatter: block per chunk; LDS cursors from precomputed base ----------
// rec = { col | T<<19 | nt<<22 , row&255 }; slot from returning LDS atomic
// (~5-way contention). Global: plain 8B stores to single-writer regions.
__global__ __launch_bounds__(256) void scatter_kernel(
    const int* __restrict__ ei, const int* __restrict__ etype,
    const int* __restrict__ ntype, const int* __restrict__ base,
    uint2* __restrict__ rec, int E, int NB, int NCH)
{
    __shared__ int cur[NBMAX];
    int tid = threadIdx.x;
    int c = blockIdx.x;
    for (int b = tid; b < NB; b += 256)
        cur[b] = base[(size_t)b * NCH + c];
    __syncthreads();
    int s = c * CH, e = min(s + CH, E);
    for (int i = s + tid; i < e; i += 256) {
        int row = ei[i], col = ei[E + i];
        int T = etype[i], nt = ntype[col];
        int b = row >> 8;
        int slot = atomicAdd(&cur[b], 1);
        uint2 r;
        r.x = (unsigned)col | ((unsigned)T << 19) | ((unsigned)nt << 22);
        r.y = (unsigned)(row & 255);
        rec[slot] = r;
    }
}

// ---- consume: block per bucket; 5 LDS atomics/edge; dense epilogue --------
__global__ __launch_bounds__(256) void consume_kernel(
    const int* __restrict__ bstart, const uint2* __restrict__ rec,
    const float* __restrict__ x, const float* __restrict__ Wc,
    const int* __restrict__ batch, const float* __restrict__ inj,
    float* __restrict__ out, int N)
{
    __shared__ float tile[256 * 57];   // row stride 57 (odd -> spread banks)
    __shared__ float Ws[55 * 32];
    int tid = threadIdx.x;
    int b = blockIdx.x;
    for (int i = tid; i < 55 * 32; i += 256) Ws[i] = Wc[i];
    for (int i = tid; i < 256 * 57; i += 256) tile[i] = 0.f;
    __syncthreads();

    int s = bstart[b], e = bstart[b + 1];
    const uint2* src = rec;
#pragma unroll 2
    for (int i = s + tid; i < e; i += 256) {
        uint2 rc = src[i];
        int col  = rc.x & 0x7FFFF;
        int T    = (rc.x >> 19) & 7;
        int nt   = (rc.x >> 22) & 7;
        int lrow = (int)(rc.y & 255);
        float4 xv = ((const float4*)x)[col];
        float* tr = tile + lrow * 57 + T * 11;
        atomicAdd(tr + 0, xv.x);
        atomicAdd(tr + 1, xv.y);
        atomicAdd(tr + 2, xv.z);
        atomicAdd(tr + 3, xv.w);
        atomicAdd(tr + 4 + nt, 1.0f);
    }
    __syncthreads();

    int nodes = N - b * 256; if (nodes > 256) nodes = 256;
    for (int oi = tid; oi < nodes * 8; oi += 256) {
        int nl = oi >> 3, cq = oi & 7;
        int n = b * 256 + nl;
        const float* ar = tile + nl * 57;
        float4 acc = {0.f, 0.f, 0.f, 0.f};
#pragma unroll 5
        for (int f = 0; f < 55; ++f) {
            float a = ar[f];
            float4 w = *(const float4*)(Ws + f * 32 + cq * 4);
            acc.x += a * w.x;
            acc.y += a * w.y;
            acc.z += a * w.z;
            acc.w += a * w.w;
        }
        int bb = batch[n];
        float4 iv = ((const float4*)inj)[bb * 8 + cq];
        float4 o;
        o.x = iv.x + 0.2f * acc.x;
        o.y = iv.y + 0.2f * acc.y;
        o.z = iv.z + 0.2f * acc.z;
        o.w = iv.w + 0.2f * acc.w;
        ((float4*)out)[(size_t)n * 8 + cq] = o;
    }
}

// ---- fallback (guards fail): out init + direct atomic scatter (R1) --------
__global__ __launch_bounds__(256) void init_kernel(
    const int* __restrict__ batch_id, const float* __restrict__ inj,
    float4* __restrict__ out, int N)
{
    int gid = blockIdx.x * 256 + threadIdx.x;
    if (gid >= N * 8) return;
    int n = gid >> 3, q = gid & 7;
    int b = batch_id[n];
    out[gid] = ((const float4*)inj)[b * 8 + q];
}

__global__ __launch_bounds__(256) void edge_direct_kernel(
    const int* __restrict__ ei, const int* __restrict__ etype,
    const int* __restrict__ ntype, const float* __restrict__ x,
    const float* __restrict__ Wc, float* __restrict__ out, int E)
{
    __shared__ float Ws[55 * 32];
    for (int i = threadIdx.x; i < 55 * 32; i += 256) Ws[i] = Wc[i];
    __syncthreads();
    unsigned total = (unsigned)E * 32u;
    unsigned stride = gridDim.x * 256u;
    for (unsigned idx = blockIdx.x * 256u + threadIdx.x; idx < total;
         idx += stride) {
        int e = (int)(idx >> 5);
        int c = (int)(idx & 31);
        int row = ei[e];
        int col = ei[E + e];
        int T = etype[e];
        int nt = ntype[col];
        float4 xv = ((const float4*)x)[col];
        const float* wb = Ws + T * 352;
        float y = xv.x * wb[c] + xv.y * wb[32 + c] + xv.z * wb[64 + c] +
                  xv.w * wb[96 + c] + wb[(4 + nt) * 32 + c];
        atomicAdd(out + (size_t)row * 32 + c, y * 0.2f);
    }
}

extern "C" void kernel_launch(void* const* d_in, const int* in_sizes, int n_in,
                              void* d_out, int out_size, void* d_ws, size_t ws_size,
                              hipStream_t stream) {
    const float* x     = (const float*)d_in[0];   // [N,4]
    const float* t     = (const float*)d_in[1];   // [8]
    const int*   ei    = (const int*)d_in[2];     // [2,E]
    const int*   etype = (const int*)d_in[3];     // [E]
    const int*   ntype = (const int*)d_in[4];     // [N]
    const int*   batch = (const int*)d_in[5];     // [N]
    const float* Wc    = (const float*)d_in[6];   // [55,32]
    const float* W1    = (const float*)d_in[7];   // [128,512]
    const float* b1    = (const float*)d_in[8];   // [512]
    const float* W2    = (const float*)d_in[9];   // [512,512]
    const float* b2    = (const float*)d_in[10];  // [512]
    const float* Wt    = (const float*)d_in[11];  // [512,32]
    float* out = (float*)d_out;

    int E = in_sizes[3];
    int N = in_sizes[4];
    int NB  = (N + 255) >> 8;                     // 256-node buckets
    int NCH = (E + CH - 1) / CH;                  // edge chunks
    size_t M = (size_t)NB * NCH;                  // scan length
    int nblkA = (int)((M + 2047) / 2048);

    // ws layout (4-byte units)
    float* ws     = (float*)d_ws;
    float* h1acc  = ws;                           // 4096
    float* h2acc  = ws + 4096;                    // 4096
    float* inj    = ws + 8192;                    // 256
    int*   counts = (int*)(ws + 8448);            // NCH*NB  (cnt[c][b])
    int*   base   = counts + M;                   // NCH*NB  (base[j])
    int*   bsums  = base + M;                     // 1024
    int*   bstart = bsums + 1024;                 // NB+1
    size_t recOff = 8448 + 2 * M + 1024 + NB + 1;
    recOff = (recOff + 1) & ~(size_t)1;           // 8B align
    uint2* rec    = (uint2*)(ws + recOff);        // E records

    size_t needBytes = recOff * 4 + (size_t)E * 8;
    bool okay = (NB <= NBMAX) && (nblkA <= 1024) && (ws_size >= needBytes);

    if (okay) {
        hipMemsetAsync(d_ws, 0, 8448 * 4, stream);   // temb accums only

        temb1_kernel<<<32, 64, 0, stream>>>(t, W1, h1acc);
        temb2_kernel<<<64, 64, 0, stream>>>(h1acc, b1, W2, h2acc);
        temb3_kernel<<<8, 256, 0, stream>>>(h2acc, b2, Wt, inj);

        hist_kernel<<<NCH, 256, 0, stream>>>(ei, counts, E, NB);
        scanA_kernel<<<nblkA, 256, 0, stream>>>(counts, bsums, (int)M, NB, NCH);
        scanB_kernel<<<1, 1024, 0, stream>>>(bsums, bstart, nblkA, NB, E);
        scanC_kernel<<<nblkA, 256, 0, stream>>>(counts, bsums, base, bstart,
                                                (int)M, NB, NCH);
        scatter_kernel<<<NCH, 256, 0, stream>>>(ei, etype, ntype, base, rec,
                                                E, NB, NCH);
        consume_kernel<<<NB, 256, 0, stream>>>(bstart, rec, x, Wc, batch, inj,
                                               out, N);
    } else {
        hipMemsetAsync(d_ws, 0, 8448 * 4, stream);
        temb1_kernel<<<32, 64, 0, stream>>>(t, W1, h1acc);
        temb2_kernel<<<64, 64, 0, stream>>>(h1acc, b1, W2, h2acc);
        temb3_kernel<<<8, 256, 0, stream>>>(h2acc, b2, Wt, inj);
        init_kernel<<<(N * 8 + 255) / 256, 256, 0, stream>>>(
            batch, inj, (float4*)out, N);
        edge_direct_kernel<<<16384, 256, 0, stream>>>(
            ei, etype, ntype, x, Wc, out, E);
    }
}